// Round 3
// baseline (462.191 us; speedup 1.0000x reference)
//
#include <hip/hip_runtime.h>

constexpr int N_NODES = 500000;
constexpr int N_Q     = 500000;
constexpr int H       = 8;
constexpr int FEAT    = 64;                       // H * MH

// ---- binning parameters -----------------------------------------------------
constexpr int TBIN   = 64;                        // nodes per bin
constexpr int SHIFT  = 6;                         // log2(TBIN)
constexpr int NB     = (N_NODES + TBIN - 1) / TBIN;   // 7813 bins
constexpr int NB_PAD = 8192;                      // scan width (1024 thr x 8)
constexpr int TP     = TBIN + 1;                  // 65: odd pad -> 2-way banks
constexpr int BT     = 512;                       // main-kernel block threads
constexpr int SLOTS  = BT / H;                    // 64 queries per sweep
constexpr int KBINS  = 4;                         // bins per main-kernel block
constexpr int NCHUNK = 64;                        // counting-sort chunks
constexpr int CHUNK  = (N_Q + NCHUNK - 1) / NCHUNK;   // 7813 items per chunk

// ---------------------------------------------------------------------------
// P1: per-chunk histogram in LDS (no global atomics).
// ---------------------------------------------------------------------------
__global__ __launch_bounds__(1024) void hist_chunks(const int* __restrict__ k_idx,
                                                    int* __restrict__ hist)   // [NCHUNK][NB]
{
    __shared__ int lh[NB];                        // 31,252 B
    const int c = blockIdx.x, tid = threadIdx.x;
    for (int i = tid; i < NB; i += 1024) lh[i] = 0;
    __syncthreads();
    const int i0 = c * CHUNK;
    const int i1 = min(i0 + CHUNK, N_Q);
    for (int i = i0 + tid; i < i1; i += 1024)
        atomicAdd(&lh[k_idx[i] >> SHIFT], 1);     // LDS atomic: ~1 op/bin/block
    __syncthreads();
    int* hrow = hist + (size_t)c * NB;
    for (int i = tid; i < NB; i += 1024) hrow[i] = lh[i];
}

// ---------------------------------------------------------------------------
// P2: per-bin totals across chunks (coalesced along b).
// ---------------------------------------------------------------------------
__global__ __launch_bounds__(256) void tot_kernel(const int* __restrict__ hist,
                                                  int* __restrict__ tot)      // [NB_PAD]
{
    const int b = blockIdx.x * 256 + threadIdx.x;
    if (b < NB) {
        int s = 0;
        for (int c = 0; c < NCHUNK; ++c) s += hist[(size_t)c * NB + b];
        tot[b] = s;
    } else if (b < NB_PAD) {
        tot[b] = 0;
    }
}

// ---------------------------------------------------------------------------
// P3: single-block exclusive scan over bins -> offsets[NB+1].
// ---------------------------------------------------------------------------
__global__ __launch_bounds__(1024) void scan_kernel(const int* __restrict__ tot,
                                                    int* __restrict__ offsets)
{
    __shared__ int sums[1024];
    const int tid  = threadIdx.x;
    const int base = tid * 8;

    int loc[8];
    int run = 0;
#pragma unroll
    for (int k = 0; k < 8; ++k) {
        loc[k] = run;
        const int idx = base + k;
        run += (idx < NB) ? tot[idx] : 0;
    }
    sums[tid] = run;
    __syncthreads();

    const int own = run;
    for (int d = 1; d < 1024; d <<= 1) {
        const int add = (tid >= d) ? sums[tid - d] : 0;
        __syncthreads();
        sums[tid] += add;
        __syncthreads();
    }
    const int excl = sums[tid] - own;

#pragma unroll
    for (int k = 0; k < 8; ++k) {
        const int idx = base + k;
        if (idx <= NB) offsets[idx] = excl + loc[k];   // offsets[NB] = N_Q
    }
}

// ---------------------------------------------------------------------------
// P4: per-chunk, per-bin base offsets (running prefix over chunks).
// ---------------------------------------------------------------------------
__global__ __launch_bounds__(256) void base_kernel(const int* __restrict__ hist,
                                                   const int* __restrict__ offsets,
                                                   int* __restrict__ base)    // [NCHUNK][NB]
{
    const int b = blockIdx.x * 256 + threadIdx.x;
    if (b < NB) {
        int run = offsets[b];
        for (int c = 0; c < NCHUNK; ++c) {
            base[(size_t)c * NB + b] = run;
            run += hist[(size_t)c * NB + b];
        }
    }
}

// ---------------------------------------------------------------------------
// P5: scatter with LDS cursors (no global atomics).
// ---------------------------------------------------------------------------
__global__ __launch_bounds__(1024) void scatter_chunks(const int* __restrict__ k_idx,
                                                       const int* __restrict__ base,
                                                       unsigned* __restrict__ vals)
{
    __shared__ int cur[NB];
    const int c = blockIdx.x, tid = threadIdx.x;
    const int* brow = base + (size_t)c * NB;
    for (int i = tid; i < NB; i += 1024) cur[i] = brow[i];
    __syncthreads();
    const int i0 = c * CHUNK;
    const int i1 = min(i0 + CHUNK, N_Q);
    for (int i = i0 + tid; i < i1; i += 1024) {
        const int j = k_idx[i];
        const int b = j >> SHIFT;
        const int p = atomicAdd(&cur[b], 1);      // LDS atomic
        vals[p] = ((unsigned)i << SHIFT) | (unsigned)(j & (TBIN - 1));
    }
}

// ---------------------------------------------------------------------------
// Main kernel helpers: reg-staged phi_k tile (T14 issue-early/write-late).
// Thread t stages rows f0=t>>4 and f0+32 of both pos & neg at col n4=(t&15)*4.
// ---------------------------------------------------------------------------
__device__ __forceinline__ void stage_load(const float* __restrict__ pk_pos,
                                           const float* __restrict__ pk_neg,
                                           int f0, int n4, int n0, int nrem,
                                           float4 r[4])
{
    const float* p0 = pk_pos + (size_t)f0 * N_NODES + n0 + n4;
    const float* p1 = pk_pos + (size_t)(f0 + 32) * N_NODES + n0 + n4;
    const float* p2 = pk_neg + (size_t)f0 * N_NODES + n0 + n4;
    const float* p3 = pk_neg + (size_t)(f0 + 32) * N_NODES + n0 + n4;
    if (n4 + 3 < nrem) {                          // nrem is a multiple of 4
        r[0] = *(const float4*)p0;
        r[1] = *(const float4*)p1;
        r[2] = *(const float4*)p2;
        r[3] = *(const float4*)p3;
    } else {
        r[0] = r[1] = r[2] = r[3] = make_float4(0.f, 0.f, 0.f, 0.f);
    }
}

__device__ __forceinline__ void stage_write(float (*lds)[FEAT][TP],
                                            int f0, int n4, const float4 r[4])
{
    float* l0 = &lds[0][f0][n4];
    float* l1 = &lds[0][f0 + 32][n4];
    float* l2 = &lds[1][f0][n4];
    float* l3 = &lds[1][f0 + 32][n4];
    l0[0] = r[0].x; l0[1] = r[0].y; l0[2] = r[0].z; l0[3] = r[0].w;
    l1[0] = r[1].x; l1[1] = r[1].y; l1[2] = r[1].z; l1[3] = r[1].w;
    l2[0] = r[2].x; l2[1] = r[2].y; l2[2] = r[2].z; l2[3] = r[2].w;
    l3[0] = r[3].x; l3[1] = r[3].y; l3[2] = r[3].z; l3[3] = r[3].w;
}

// ---------------------------------------------------------------------------
// K-main: KBINS bins per block, single LDS buffer, software-pipelined:
//   stage_write(bin i) | stage_load(bin i+1) | vals(i+1) -> barrier ->
//   compute(bin i) -> prefetch q_phi/deg for sweep-0 of bin i+1 -> barrier.
// Next-bin staging & gather latency hides under compute of the current bin.
// ---------------------------------------------------------------------------
__global__ __launch_bounds__(BT, 8) void iskde_binned(
    const float* __restrict__ q_phi,
    const float* __restrict__ pk_pos,                 // [64][N_NODES]
    const float* __restrict__ pk_neg,
    const float* __restrict__ deg_pos,                // [N_NODES][H]
    const float* __restrict__ deg_neg,
    const unsigned* __restrict__ vals,                // bin-sorted (q<<6|dj)
    const int* __restrict__ offsets,                  // [NB+1]
    float* __restrict__ out)                          // [2][N_Q][H]
{
    __shared__ float lds[2][FEAT][TP];                // 33,280 B -> 4 blocks/CU

    const int tid  = threadIdx.x;
    const int h    = tid & 7;
    const int slot = tid >> 3;                        // 0..63
    const int f0   = tid >> 4;                        // 0..31
    const int n4   = (tid & 15) * 4;                  // 0..60

    const int b0 = blockIdx.x * KBINS;
    const int nb = min(KBINS, NB - b0);

    // ---- prologue: issue bin-0 staging + sweep-0 gather chain ----
    float4 r[4];
    {
        const int n0   = b0 * TBIN;
        const int nrem = min(TBIN, N_NODES - n0);
        stage_load(pk_pos, pk_neg, f0, n4, n0, nrem, r);
    }

    int off0 = offsets[b0];
    int off1 = offsets[b0 + 1];
    int cnt  = off1 - off0;
    unsigned v = (slot < cnt) ? vals[off0 + slot] : 0u;
    int q  = (int)(v >> SHIFT);                       // invalid lanes -> q=0, safe
    int dj = (int)(v & (TBIN - 1));
    const float4* qp = (const float4*)(q_phi + (size_t)q * FEAT + h * 8);
    float4 a0 = qp[0];
    float4 a1 = qp[1];
    float dgp = deg_pos[(size_t)(b0 * TBIN + dj) * H + h];
    float dgn = deg_neg[(size_t)(b0 * TBIN + dj) * H + h];

    for (int i = 0; i < nb; ++i) {
        const int b  = b0 + i;
        const int n0 = b * TBIN;

        stage_write(lds, f0, n4, r);                  // waits bin-i loads only

        if (i + 1 < nb) {                             // issue next-bin staging
            const int n0n   = (b + 1) * TBIN;
            const int nremn = min(TBIN, N_NODES - n0n);
            stage_load(pk_pos, pk_neg, f0, n4, n0n, nremn, r);
        }

        // prefetch next bin's sweep-0 vals (pre-barrier; hides under compute)
        int off0n = 0, cntn = 0;
        unsigned vn = 0u;
        if (i + 1 < nb) {
            off0n = off1;
            const int off1n = offsets[min(b + 2, NB)];
            cntn = off1n - off0n;
            if (slot < cntn) vn = vals[off0n + slot];
            off1 = off1n;
        }
        __syncthreads();

        // ---- sweep 0 (fully prefetched) ----
        if (slot < cnt) {
            const float* lp = &lds[0][h * 8][dj];
            const float* ln = &lds[1][h * 8][dj];
            float sp = a0.x*lp[0]      + a0.y*lp[TP]     + a0.z*lp[2*TP] + a0.w*lp[3*TP]
                     + a1.x*lp[4*TP]   + a1.y*lp[5*TP]   + a1.z*lp[6*TP] + a1.w*lp[7*TP];
            float sn = a0.x*ln[0]      + a0.y*ln[TP]     + a0.z*ln[2*TP] + a0.w*ln[3*TP]
                     + a1.x*ln[4*TP]   + a1.y*ln[5*TP]   + a1.z*ln[6*TP] + a1.w*ln[7*TP];
            const float dp = fmaxf(dgp, 1.0f);
            const float dn = fmaxf(dgn, 1.0f);
            const size_t o = (size_t)q * H + h;
            __builtin_nontemporal_store(sp / dp, &out[o]);
            __builtin_nontemporal_store(sn / dn, &out[(size_t)N_Q * H + o]);
        }

        // ---- tail sweeps (Poisson(64) overflow) ----
        for (int it0 = SLOTS; it0 < cnt; it0 += SLOTS) {
            const int qi  = it0 + slot;
            const bool ok = qi < cnt;
            const unsigned vt = ok ? vals[off0 + qi] : 0u;
            const int qt  = (int)(vt >> SHIFT);
            const int djt = (int)(vt & (TBIN - 1));
            const float4* qpt = (const float4*)(q_phi + (size_t)qt * FEAT + h * 8);
            const float4 c0 = qpt[0];
            const float4 c1 = qpt[1];
            const float* lp = &lds[0][h * 8][djt];
            const float* ln = &lds[1][h * 8][djt];
            float sp = c0.x*lp[0]      + c0.y*lp[TP]     + c0.z*lp[2*TP] + c0.w*lp[3*TP]
                     + c1.x*lp[4*TP]   + c1.y*lp[5*TP]   + c1.z*lp[6*TP] + c1.w*lp[7*TP];
            float sn = c0.x*ln[0]      + c0.y*ln[TP]     + c0.z*ln[2*TP] + c0.w*ln[3*TP]
                     + c1.x*ln[4*TP]   + c1.y*ln[5*TP]   + c1.z*ln[6*TP] + c1.w*ln[7*TP];
            const float dp = fmaxf(deg_pos[(size_t)(n0 + djt) * H + h], 1.0f);
            const float dn = fmaxf(deg_neg[(size_t)(n0 + djt) * H + h], 1.0f);
            if (ok) {
                const size_t o = (size_t)qt * H + h;
                __builtin_nontemporal_store(sp / dp, &out[o]);
                __builtin_nontemporal_store(sn / dn, &out[(size_t)N_Q * H + o]);
            }
        }

        // ---- prefetch next bin's sweep-0 q_phi/deg (vn has arrived by now) ----
        if (i + 1 < nb) {
            q  = (int)(vn >> SHIFT);
            dj = (int)(vn & (TBIN - 1));
            const float4* qpn = (const float4*)(q_phi + (size_t)q * FEAT + h * 8);
            a0 = qpn[0];
            a1 = qpn[1];
            dgp = deg_pos[(size_t)((b + 1) * TBIN + dj) * H + h];
            dgn = deg_neg[(size_t)((b + 1) * TBIN + dj) * H + h];
            off0 = off0n;
            cnt  = cntn;
        }
        __syncthreads();                              // LDS free for next write
    }
}

// ---------------------------------------------------------------------------
// Fallback (no workspace): direct strided gather, wave per query.
// ---------------------------------------------------------------------------
__global__ __launch_bounds__(256, 4) void iskde_gather_kernel(
    const float* __restrict__ q_phi,
    const float* __restrict__ pk_pos,
    const float* __restrict__ pk_neg,
    const float* __restrict__ deg_pos,
    const float* __restrict__ deg_neg,
    const int*   __restrict__ k_idx,
    float*       __restrict__ out)
{
    const int wave_in_blk = threadIdx.x >> 6;
    const int lane        = threadIdx.x & 63;
    const int q           = blockIdx.x * 4 + wave_in_blk;
    if (q >= N_Q) return;

    const int j = k_idx[q];
    const float qv = q_phi[(size_t)q * FEAT + lane];
    const size_t col = (size_t)lane * (size_t)N_NODES + (size_t)j;
    const float pv = pk_pos[col];
    const float nv = pk_neg[col];

    float sp = qv * pv;
    float sn = qv * nv;
    sp += __shfl_xor(sp, 1, 64);
    sn += __shfl_xor(sn, 1, 64);
    sp += __shfl_xor(sp, 2, 64);
    sn += __shfl_xor(sn, 2, 64);
    sp += __shfl_xor(sp, 4, 64);
    sn += __shfl_xor(sn, 4, 64);

    if ((lane & 7) == 0) {
        const int h = lane >> 3;
        const float dp = fmaxf(deg_pos[(size_t)j * H + h], 1.0f);
        const float dn = fmaxf(deg_neg[(size_t)j * H + h], 1.0f);
        const size_t o = (size_t)q * H + h;
        out[o]                   = sp / dp;
        out[(size_t)N_Q * H + o] = sn / dn;
    }
}

extern "C" void kernel_launch(void* const* d_in, const int* in_sizes, int n_in,
                              void* d_out, int out_size, void* d_ws, size_t ws_size,
                              hipStream_t stream) {
    const float* q_phi   = (const float*)d_in[0];
    const float* pk_pos  = (const float*)d_in[1];
    const float* pk_neg  = (const float*)d_in[2];
    const float* deg_pos = (const float*)d_in[3];
    const float* deg_neg = (const float*)d_in[4];
    const int*   k_idx   = (const int*)d_in[5];
    float*       out     = (float*)d_out;

    // ws ints: hist[NCHUNK*NB] | base[NCHUNK*NB] | tot[NB_PAD] | offsets[NB_PAD+8] | vals[N_Q]
    const size_t CN   = (size_t)NCHUNK * NB;
    const size_t need = (2 * CN + NB_PAD + NB_PAD + 8 + (size_t)N_Q) * sizeof(int);  // ~6.1 MB

    if (ws_size >= need) {
        int*      hist    = (int*)d_ws;
        int*      base    = hist + CN;
        int*      tot     = base + CN;
        int*      offsets = tot + NB_PAD;
        unsigned* vals    = (unsigned*)(offsets + NB_PAD + 8);

        hist_chunks<<<NCHUNK, 1024, 0, stream>>>(k_idx, hist);
        tot_kernel<<<NB_PAD / 256, 256, 0, stream>>>(hist, tot);
        scan_kernel<<<1, 1024, 0, stream>>>(tot, offsets);
        base_kernel<<<NB_PAD / 256, 256, 0, stream>>>(hist, offsets, base);
        scatter_chunks<<<NCHUNK, 1024, 0, stream>>>(k_idx, base, vals);

        const int mgrid = (NB + KBINS - 1) / KBINS;   // 1954
        iskde_binned<<<mgrid, BT, 0, stream>>>(
            q_phi, pk_pos, pk_neg, deg_pos, deg_neg, vals, offsets, out);
    } else {
        const int blocks = (N_Q + 3) / 4;
        iskde_gather_kernel<<<blocks, 256, 0, stream>>>(
            q_phi, pk_pos, pk_neg, deg_pos, deg_neg, k_idx, out);
    }
}